// Round 1
// baseline (709.841 us; speedup 1.0000x reference)
//
#include <hip/hip_runtime.h>
#include <math.h>

// TemporalAttentionPooling: B=32, L=4096, D=1024, fp32.
// out[b,d] = sum_l softmax_l( mask ? (seq[b,l,:]·q)/32 : -inf ) * seq[b,l,d]
//
// Single-pass online-softmax: each block handles one (b, split) chunk of L,
// streaming rows once from HBM. Partials (running max m, running sum, and
// unnormalized acc[D]) go to d_ws; a tiny combine kernel merges splits.

#define B_ 32
#define L_ 4096
#define D_ 1024
#define T_ 256      // threads per block; thread t owns columns [4t, 4t+4)
#define ROWS 8      // rows processed per barrier round

__global__ __launch_bounds__(T_) void tap_partial(
    const float* __restrict__ seq, const int* __restrict__ mask,
    const float* __restrict__ query, float* __restrict__ ws_m,
    float* __restrict__ ws_s, float* __restrict__ ws_acc, int S)
{
    const int tid  = threadIdx.x;
    const int bs   = blockIdx.x;          // b*S + split
    const int b    = bs / S;
    const int sp   = bs - b * S;
    const int rows_per = L_ / S;          // S is a power of two <= 1024
    const int l0   = sp * rows_per;

    const int wave = tid >> 6;
    const int lane = tid & 63;

    // query fragment for my 4 columns (reused every row)
    const float4 q = *reinterpret_cast<const float4*>(query + tid * 4);

    float  m   = -INFINITY;
    float  sum = 0.0f;
    float4 acc = make_float4(0.f, 0.f, 0.f, 0.f);

    __shared__ float red[2][4][ROWS];     // [parity][wave][row]

    int parity = 0;
    for (int l = l0; l < l0 + rows_per; l += ROWS, parity ^= 1) {
        float4 v[ROWS];
        float  p[ROWS];
        const float* base = seq + ((size_t)b * L_ + l) * D_ + tid * 4;
#pragma unroll
        for (int r = 0; r < ROWS; ++r) {
            v[r] = *reinterpret_cast<const float4*>(base + (size_t)r * D_);
            p[r] = v[r].x * q.x + v[r].y * q.y + v[r].z * q.z + v[r].w * q.w;
        }
        // 64-lane butterfly reduce of all ROWS partials
#pragma unroll
        for (int off = 32; off > 0; off >>= 1) {
#pragma unroll
            for (int r = 0; r < ROWS; ++r)
                p[r] += __shfl_down(p[r], off, 64);
        }
        if (lane == 0) {
#pragma unroll
            for (int r = 0; r < ROWS; ++r) red[parity][wave][r] = p[r];
        }
        __syncthreads();   // (double-buffered red -> one barrier per iter)

        float s[ROWS];
#pragma unroll
        for (int r = 0; r < ROWS; ++r) {
            s[r] = (red[parity][0][r] + red[parity][1][r]) +
                   (red[parity][2][r] + red[parity][3][r]);
            s[r] *= 0.03125f;                       // 1/sqrt(1024)
            if (mask[b * L_ + l + r] == 0) s[r] = -INFINITY;
        }

        float pm = s[0];
#pragma unroll
        for (int r = 1; r < ROWS; ++r) pm = fmaxf(pm, s[r]);
        float m_new = fmaxf(m, pm);
        if (m_new != -INFINITY) {                   // else: all weights 0, skip
            float scale = __expf(m - m_new);        // m=-inf -> 0
            float w[ROWS];
#pragma unroll
            for (int r = 0; r < ROWS; ++r) w[r] = __expf(s[r] - m_new); // -inf -> 0
            float ws = 0.f;
#pragma unroll
            for (int r = 0; r < ROWS; ++r) ws += w[r];
            sum = sum * scale + ws;
            float ax = acc.x * scale, ay = acc.y * scale,
                  az = acc.z * scale, aw = acc.w * scale;
#pragma unroll
            for (int r = 0; r < ROWS; ++r) {
                ax += w[r] * v[r].x;
                ay += w[r] * v[r].y;
                az += w[r] * v[r].z;
                aw += w[r] * v[r].w;
            }
            acc = make_float4(ax, ay, az, aw);
            m = m_new;
        }
    }

    if (tid == 0) { ws_m[bs] = m; ws_s[bs] = sum; }
    *reinterpret_cast<float4*>(ws_acc + (size_t)bs * D_ + tid * 4) = acc;
}

__global__ __launch_bounds__(T_) void tap_combine(
    const float* __restrict__ ws_m, const float* __restrict__ ws_s,
    const float* __restrict__ ws_acc, float* __restrict__ out, int S)
{
    const int b   = blockIdx.x;
    const int tid = threadIdx.x;

    float M = -INFINITY;
    for (int s = 0; s < S; ++s) M = fmaxf(M, ws_m[b * S + s]);

    float  total = 0.f;
    float4 num   = make_float4(0.f, 0.f, 0.f, 0.f);
    for (int s = 0; s < S; ++s) {
        float ms = ws_m[b * S + s];
        if (ms == -INFINITY) continue;              // empty split
        float w = __expf(ms - M);
        total += ws_s[b * S + s] * w;
        float4 a = *reinterpret_cast<const float4*>(
            ws_acc + (size_t)(b * S + s) * D_ + tid * 4);
        num.x += w * a.x; num.y += w * a.y;
        num.z += w * a.z; num.w += w * a.w;
    }
    float inv = 1.0f / total;
    float4 o = make_float4(num.x * inv, num.y * inv, num.z * inv, num.w * inv);
    *reinterpret_cast<float4*>(out + (size_t)b * D_ + tid * 4) = o;
}

extern "C" void kernel_launch(void* const* d_in, const int* in_sizes, int n_in,
                              void* d_out, int out_size, void* d_ws, size_t ws_size,
                              hipStream_t stream) {
    const float* seq   = (const float*)d_in[0];
    const int*   mask  = (const int*)d_in[1];
    const float* query = (const float*)d_in[2];
    float*       out   = (float*)d_out;

    // pick split count S (power of two) that fits the workspace
    int S = 64;
    while (S > 1 && (size_t)B_ * S * (D_ + 2) * sizeof(float) > ws_size) S >>= 1;

    float* ws_m   = (float*)d_ws;
    float* ws_s   = ws_m + (size_t)B_ * S;
    float* ws_acc = ws_s + (size_t)B_ * S;   // 16B-aligned (2*B*S*4 = 16 KiB)

    tap_partial<<<B_ * S, T_, 0, stream>>>(seq, mask, query, ws_m, ws_s, ws_acc, S);
    tap_combine<<<B_,     T_, 0, stream>>>(ws_m, ws_s, ws_acc, out, S);
}